// Round 7
// baseline (191.996 us; speedup 1.0000x reference)
//
#include <hip/hip_runtime.h>

#define KK 27
#define PD 4   // A/B fragment pipeline depth (taps)
#define ID 8   // neighbor-index lookahead ring (taps)

typedef short bf16x8 __attribute__((ext_vector_type(8)));   // 8 bf16 in 4 VGPRs
typedef float f32x4  __attribute__((ext_vector_type(4)));

__device__ inline unsigned short f2bf(float f) {            // RNE fp32 -> bf16
    unsigned u = __float_as_uint(f);
    unsigned r = u + 0x7fffu + ((u >> 16) & 1u);
    return (unsigned short)(r >> 16);
}

// ---- Kernel 1: fused prep ----
// blocks [0, KK): weight [27][cin][cout] fp32 -> wTb [27][cout][cin] bf16
//                 (block 0 also zeroes tot[64] for conv_k's atomics)
// blocks [KK, ...): x [32][N] fp32 -> xTb [N][32] bf16 (transpose + cast)
__global__ __launch_bounds__(256) void prep_k(const float* __restrict__ in,
                                              const float* __restrict__ w,
                                              unsigned short* __restrict__ xTb,
                                              unsigned short* __restrict__ wTb,
                                              float* __restrict__ tot, int N) {
    const int bx = blockIdx.x;
    if (bx < KK) {
        if (bx == 0 && threadIdx.x < 64) tot[threadIdx.x] = 0.f;
        for (int i = threadIdx.x; i < 1024; i += 256) {
            int cin = i >> 5, cout = i & 31;
            wTb[bx * 1024 + cout * 32 + cin] = f2bf(w[bx * 1024 + cin * 32 + cout]);
        }
        return;
    }
    __shared__ float tile[32][33];
    int n0 = (bx - KK) * 32;
    int tx = threadIdx.x & 31;
    int ty = threadIdx.x >> 5;  // 0..7
#pragma unroll
    for (int c = ty; c < 32; c += 8) {
        int n = n0 + tx;
        tile[c][tx] = (n < N) ? in[(long)c * N + n] : 0.f;
    }
    __syncthreads();
#pragma unroll
    for (int nn = ty; nn < 32; nn += 8) {
        int n = n0 + nn;
        if (n < N) xTb[(long)n * 32 + tx] = f2bf(tile[tx][nn]);
    }
}

// ---- Kernel 2: MFMA conv, deep-pipelined + BN partials via atomics ----
// 2 waves/block, 32 nodes/wave. Fully unrolled 27-tap loop with ring buffers:
// neigh indices prefetched ID=8 taps ahead, A (gathered node rows) and B
// (weights) PD=4 taps ahead -> 4 outstanding 1KB gathers/wave instead of 1.
// Invalid-node masking deferred to the epilogue (indices clamped in-loop).
__global__ __launch_bounds__(128, 3) void conv_k(const unsigned short* __restrict__ xTb,
                                                 const int* __restrict__ neigh,
                                                 const unsigned short* __restrict__ wTb,
                                                 float* __restrict__ y,    // [32][N]
                                                 float* __restrict__ tot,  // [64]
                                                 int N) {
    __shared__ float ct[2][32][33];

    const int tid  = threadIdx.x;
    const int L    = tid & 63;
    const int wv   = tid >> 6;         // wave in block
    const int r16  = L & 15;
    const int quad = L >> 4;           // 0..3
    const int base = blockIdx.x * 64 + wv * 32;
    const int n0c  = min(base + r16, N - 1);
    const int n1c  = min(base + 16 + r16, N - 1);
    const long nb0 = (long)n0c * KK;
    const long nb1 = (long)n1c * KK;

    f32x4 acc00 = {0.f, 0.f, 0.f, 0.f};
    f32x4 acc01 = acc00, acc10 = acc00, acc11 = acc00;

    int    ja[ID], jb[ID];
    bf16x8 A0[PD], A1[PD], B0[PD], B1[PD];

    // prologue: index lookahead ring
#pragma unroll
    for (int t = 0; t < ID; ++t) {
        ja[t] = neigh[nb0 + t];
        jb[t] = neigh[nb1 + t];
    }
    // prologue: first PD stages of A/B
#pragma unroll
    for (int t = 0; t < PD; ++t) {
        A0[t] = *(const bf16x8*)(xTb + (long)ja[t] * 32 + quad * 8);
        A1[t] = *(const bf16x8*)(xTb + (long)jb[t] * 32 + quad * 8);
        const unsigned short* wn = wTb + t * 1024;
        B0[t] = *(const bf16x8*)(wn + r16 * 32 + quad * 8);
        B1[t] = *(const bf16x8*)(wn + (16 + r16) * 32 + quad * 8);
    }

#pragma unroll
    for (int k = 0; k < KK; ++k) {
        const int s = k % PD;
        acc00 = __builtin_amdgcn_mfma_f32_16x16x32_bf16(A0[s], B0[s], acc00, 0, 0, 0);
        acc01 = __builtin_amdgcn_mfma_f32_16x16x32_bf16(A0[s], B1[s], acc01, 0, 0, 0);
        acc10 = __builtin_amdgcn_mfma_f32_16x16x32_bf16(A1[s], B0[s], acc10, 0, 0, 0);
        acc11 = __builtin_amdgcn_mfma_f32_16x16x32_bf16(A1[s], B1[s], acc11, 0, 0, 0);

        if (k + ID < KK) {               // refill index ring
            ja[k % ID] = neigh[nb0 + k + ID];
            jb[k % ID] = neigh[nb1 + k + ID];
        }
        if (k + PD < KK) {               // refill A/B stage s for tap k+PD
            const int ii = ja[(k + PD) % ID];
            const int jj = jb[(k + PD) % ID];
            A0[s] = *(const bf16x8*)(xTb + (long)ii * 32 + quad * 8);
            A1[s] = *(const bf16x8*)(xTb + (long)jj * 32 + quad * 8);
            const unsigned short* wn = wTb + (k + PD) * 1024;
            B0[s] = *(const bf16x8*)(wn + r16 * 32 + quad * 8);
            B1[s] = *(const bf16x8*)(wn + (16 + r16) * 32 + quad * 8);
        }
    }

    // epilogue: zero contributions of out-of-range nodes
    // C/D layout: cout = L&15 (+16 for the B1 tiles), node-in-tile = quad*4+r
#pragma unroll
    for (int r = 0; r < 4; ++r) {
        if (base + quad * 4 + r >= N)      { acc00[r] = 0.f; acc01[r] = 0.f; }
        if (base + 16 + quad * 4 + r >= N) { acc10[r] = 0.f; acc11[r] = 0.f; }
    }

    // BN partials: sum over this wave's 32 nodes, then atomics into tot[64]
    float s0 = 0.f, q0 = 0.f, s1 = 0.f, q1 = 0.f;
#pragma unroll
    for (int r = 0; r < 4; ++r) {
        s0 += acc00[r] + acc10[r];
        q0 += acc00[r] * acc00[r] + acc10[r] * acc10[r];
        s1 += acc01[r] + acc11[r];
        q1 += acc01[r] * acc01[r] + acc11[r] * acc11[r];
    }
#pragma unroll
    for (int off = 16; off < 64; off <<= 1) {
        s0 += __shfl_xor(s0, off, 64);
        q0 += __shfl_xor(q0, off, 64);
        s1 += __shfl_xor(s1, off, 64);
        q1 += __shfl_xor(q1, off, 64);
    }
    if (L < 16) {
        atomicAdd(tot + L,      s0);
        atomicAdd(tot + L + 16, s1);
        atomicAdd(tot + L + 32, q0);
        atomicAdd(tot + L + 48, q1);
    }

    // y stores via LDS transpose: [cout][node], node contiguous
#pragma unroll
    for (int r = 0; r < 4; ++r) {
        ct[wv][quad * 4 + r][r16]           = acc00[r];
        ct[wv][quad * 4 + r][16 + r16]      = acc01[r];
        ct[wv][16 + quad * 4 + r][r16]      = acc10[r];
        ct[wv][16 + quad * 4 + r][16 + r16] = acc11[r];
    }
    __syncthreads();
    const int node = L & 31;
    const int half = L >> 5;
    const int gn = base + node;
#pragma unroll
    for (int i = 0; i < 16; ++i) {
        const int cout = i * 2 + half;
        if (gn < N) y[(long)cout * N + gn] = ct[wv][node][cout];
    }
}

// ---- Kernel 3: finalize stats + normalize y in place ----
__global__ __launch_bounds__(256) void norm_k(float* __restrict__ y,
                                              const float* __restrict__ tot,
                                              const float* __restrict__ gamma,
                                              const float* __restrict__ beta, int N) {
    const int d = blockIdx.y;
    const float mean = tot[d] / (float)N;
    const float var  = tot[d + 32] / (float)N - mean * mean;
    const float sc   = gamma[d] * rsqrtf(var + 1e-3f);
    const float sh   = beta[d] - mean * sc;

    int i = blockIdx.x * blockDim.x + threadIdx.x;
    int base = i * 4;
    if (base + 3 < N) {
        float4* p = (float4*)(y + (long)d * N + base);
        float4 v = *p;
        v.x = fmaf(v.x, sc, sh);
        v.y = fmaf(v.y, sc, sh);
        v.z = fmaf(v.z, sc, sh);
        v.w = fmaf(v.w, sc, sh);
        *p = v;
    } else if (base < N) {
        for (int t = base; t < N; ++t) y[(long)d * N + t] = fmaf(y[(long)d * N + t], sc, sh);
    }
}

// ---- launcher ----
extern "C" void kernel_launch(void* const* d_in, const int* in_sizes, int n_in,
                              void* d_out, int out_size, void* d_ws, size_t ws_size,
                              hipStream_t stream) {
    const float* data_in = (const float*)d_in[0];
    const int*   neigh   = (const int*)d_in[1];
    const float* weight  = (const float*)d_in[2];
    const float* gamma   = (const float*)d_in[3];
    const float* beta    = (const float*)d_in[4];
    float* out = (float*)d_out;

    const int N = in_sizes[1] / KK;
    const int nblk32 = (N + 31) / 32;        // x-prep tiles
    const int nblk64 = (N + 63) / 64;        // conv blocks (2 waves x 32 nodes)

    char* ws = (char*)d_ws;
    unsigned short* xTb = (unsigned short*)ws;                     // N*32 bf16
    unsigned short* wTb = (unsigned short*)(ws + (size_t)N * 64);  // 27*1024 bf16
    float* tot = (float*)(ws + (size_t)N * 64 + 55296);            // 64 floats

    prep_k<<<KK + nblk32, 256, 0, stream>>>(data_in, weight, xTb, wTb, tot, N);
    conv_k<<<nblk64, 128, 0, stream>>>(xTb, neigh, wTb, out, tot, N);
    dim3 ngrid(((N + 3) / 4 + 255) / 256, 32);
    norm_k<<<ngrid, 256, 0, stream>>>(out, tot, gamma, beta, N);
}

// Round 9
// 178.417 us; speedup vs baseline: 1.0761x; 1.0761x over previous
//
#include <hip/hip_runtime.h>

#define KK 27

typedef short bf16x8 __attribute__((ext_vector_type(8)));   // 8 bf16 in 4 VGPRs
typedef float f32x4  __attribute__((ext_vector_type(4)));

__device__ inline unsigned short f2bf(float f) {            // RNE fp32 -> bf16
    unsigned u = __float_as_uint(f);
    unsigned r = u + 0x7fffu + ((u >> 16) & 1u);
    return (unsigned short)(r >> 16);
}

// async 16B/lane global->LDS (LDS dst = wave-uniform base + lane*16)
__device__ __forceinline__ void gload16(const void* g, void* l) {
    __builtin_amdgcn_global_load_lds(
        (const __attribute__((address_space(1))) void*)g,
        (__attribute__((address_space(3))) void*)l, 16, 0, 0);
}

// ---- Kernel 1: fused prep ----
__global__ __launch_bounds__(256) void prep_k(const float* __restrict__ in,
                                              const float* __restrict__ w,
                                              unsigned short* __restrict__ xTb,
                                              unsigned short* __restrict__ wTb,
                                              float* __restrict__ tot, int N) {
    const int bx = blockIdx.x;
    if (bx < KK) {
        if (bx == 0 && threadIdx.x < 64) tot[threadIdx.x] = 0.f;
        for (int i = threadIdx.x; i < 1024; i += 256) {
            int cin = i >> 5, cout = i & 31;
            wTb[bx * 1024 + cout * 32 + cin] = f2bf(w[bx * 1024 + cin * 32 + cout]);
        }
        return;
    }
    __shared__ float tile[32][33];
    int n0 = (bx - KK) * 32;
    int tx = threadIdx.x & 31;
    int ty = threadIdx.x >> 5;  // 0..7
#pragma unroll
    for (int c = ty; c < 32; c += 8) {
        int n = n0 + tx;
        tile[c][tx] = (n < N) ? in[(long)c * N + n] : 0.f;
    }
    __syncthreads();
#pragma unroll
    for (int nn = ty; nn < 32; nn += 8) {
        int n = n0 + nn;
        if (n < N) xTb[(long)n * 32 + tx] = f2bf(tile[tx][nn]);
    }
}

// ---- Kernel 2: MFMA conv via LDS-DMA gather pipeline ----
// 2 waves/block, 32 nodes/wave. 4 phases x ~7 taps: issue 28 global_load_lds
// (A0,A1,B0,B1 tiles, 1KB each) into a per-wave LDS ring, ONE vmcnt(0) drain,
// then pure ds_read+MFMA compute. LDS-DMA uses no result VGPRs -> the compiler
// cannot de-pipeline it by register throttling (rounds 4/5/7 failure mode).
// Explicit fences: lgkmcnt(0) before reusing the ring (prior phase's ds_reads
// executed), vmcnt(0) before consuming it (DMA landed). Both carry "memory"
// clobbers so the compiler cannot reorder LDS ops across them.
__global__ __launch_bounds__(128, 4) void conv_k(const unsigned short* __restrict__ xTb,
                                                 const int* __restrict__ neigh,
                                                 const unsigned short* __restrict__ wTb,
                                                 float* __restrict__ y,    // [32][N]
                                                 float* __restrict__ tot,  // [64]
                                                 int N) {
    __shared__ __align__(16) char ring[2][7][4][1024];  // [wave][slot][A0,A1,B0,B1][64*16B]
    __shared__ int lidx[64 * KK];                       // block's 64 nodes x 27 idx
    __shared__ float ct[2][32][33];                     // epilogue transpose

    const int tid  = threadIdx.x;
    const int L    = tid & 63;
    const int wv   = tid >> 6;
    const int r16  = L & 15;
    const int quad = L >> 4;
    const int base = blockIdx.x * 64;

    // cooperative coalesced neigh stage: 64*27 contiguous ints
    {
        const long g0  = (long)base * KK;
        const long lim = (long)N * KK;
        for (int j = tid; j < 64 * KK; j += 128) {
            long g = g0 + j;
            lidx[j] = (g < lim) ? neigh[g] : 0;
        }
    }
    __syncthreads();

    const int nn0 = wv * 32 + r16;   // block-local node, M-tile 0
    const int nn1 = nn0 + 16;        // M-tile 1

    f32x4 acc00 = {0.f, 0.f, 0.f, 0.f};
    f32x4 acc01 = acc00, acc10 = acc00, acc11 = acc00;

    char* myring = &ring[wv][0][0][0];

#define PHASE(KBEG, CNT) do {                                                   \
    int i0[CNT], i1[CNT];                                                       \
    _Pragma("unroll")                                                           \
    for (int t = 0; t < CNT; ++t) {                                             \
        i0[t] = lidx[nn0 * KK + (KBEG) + t];                                    \
        i1[t] = lidx[nn1 * KK + (KBEG) + t];                                    \
    }                                                                           \
    /* ring about to be overwritten: prior phase's ds_reads must have run */    \
    asm volatile("s_waitcnt lgkmcnt(0)" ::: "memory");                          \
    _Pragma("unroll")                                                           \
    for (int t = 0; t < CNT; ++t) {                                             \
        char* slot = myring + t * 4096;                                         \
        gload16(xTb + (long)i0[t] * 32 + quad * 8, slot +        L * 16);       \
        gload16(xTb + (long)i1[t] * 32 + quad * 8, slot + 1024 + L * 16);       \
        const unsigned short* wkk = wTb + ((KBEG) + t) * 1024;                  \
        gload16(wkk + r16 * 32 + quad * 8,        slot + 2048 + L * 16);        \
        gload16(wkk + (16 + r16) * 32 + quad * 8, slot + 3072 + L * 16);        \
    }                                                                           \
    /* consume only after every DMA of this phase has landed in LDS */          \
    asm volatile("s_waitcnt vmcnt(0)" ::: "memory");                            \
    _Pragma("unroll")                                                           \
    for (int t = 0; t < CNT; ++t) {                                             \
        const char* slot = myring + t * 4096;                                   \
        bf16x8 a0 = *(const bf16x8*)(slot +        L * 16);                     \
        bf16x8 a1 = *(const bf16x8*)(slot + 1024 + L * 16);                     \
        bf16x8 b0 = *(const bf16x8*)(slot + 2048 + L * 16);                     \
        bf16x8 b1 = *(const bf16x8*)(slot + 3072 + L * 16);                     \
        acc00 = __builtin_amdgcn_mfma_f32_16x16x32_bf16(a0, b0, acc00, 0, 0, 0);\
        acc01 = __builtin_amdgcn_mfma_f32_16x16x32_bf16(a0, b1, acc01, 0, 0, 0);\
        acc10 = __builtin_amdgcn_mfma_f32_16x16x32_bf16(a1, b0, acc10, 0, 0, 0);\
        acc11 = __builtin_amdgcn_mfma_f32_16x16x32_bf16(a1, b1, acc11, 0, 0, 0);\
    }                                                                           \
} while (0)

    PHASE(0, 7);
    PHASE(7, 7);
    PHASE(14, 7);
    PHASE(21, 6);
#undef PHASE

    const int wbase = base + wv * 32;

    // zero contributions of out-of-range nodes
    // C/D layout: cout = r16 (+16 for B1 tiles), node-in-tile = quad*4 + r
#pragma unroll
    for (int r = 0; r < 4; ++r) {
        if (wbase + quad * 4 + r >= N)      { acc00[r] = 0.f; acc01[r] = 0.f; }
        if (wbase + 16 + quad * 4 + r >= N) { acc10[r] = 0.f; acc11[r] = 0.f; }
    }

    // BN partials: per-wave sums -> atomics into tot[64]
    float s0 = 0.f, q0 = 0.f, s1 = 0.f, q1 = 0.f;
#pragma unroll
    for (int r = 0; r < 4; ++r) {
        s0 += acc00[r] + acc10[r];
        q0 += acc00[r] * acc00[r] + acc10[r] * acc10[r];
        s1 += acc01[r] + acc11[r];
        q1 += acc01[r] * acc01[r] + acc11[r] * acc11[r];
    }
#pragma unroll
    for (int off = 16; off < 64; off <<= 1) {
        s0 += __shfl_xor(s0, off, 64);
        q0 += __shfl_xor(q0, off, 64);
        s1 += __shfl_xor(s1, off, 64);
        q1 += __shfl_xor(q1, off, 64);
    }
    if (L < 16) {
        atomicAdd(tot + L,      s0);
        atomicAdd(tot + L + 16, s1);
        atomicAdd(tot + L + 32, q0);
        atomicAdd(tot + L + 48, q1);
    }

    // y stores via LDS transpose: [cout][node], node contiguous
#pragma unroll
    for (int r = 0; r < 4; ++r) {
        ct[wv][quad * 4 + r][r16]           = acc00[r];
        ct[wv][quad * 4 + r][16 + r16]      = acc01[r];
        ct[wv][16 + quad * 4 + r][r16]      = acc10[r];
        ct[wv][16 + quad * 4 + r][16 + r16] = acc11[r];
    }
    __syncthreads();
    const int node = L & 31;
    const int half = L >> 5;
    const int gn = wbase + node;
#pragma unroll
    for (int i = 0; i < 16; ++i) {
        const int cout = i * 2 + half;
        if (gn < N) y[(long)cout * N + gn] = ct[wv][node][cout];
    }
}

// ---- Kernel 3: finalize stats + normalize y in place ----
__global__ __launch_bounds__(256) void norm_k(float* __restrict__ y,
                                              const float* __restrict__ tot,
                                              const float* __restrict__ gamma,
                                              const float* __restrict__ beta, int N) {
    const int d = blockIdx.y;
    const float mean = tot[d] / (float)N;
    const float var  = tot[d + 32] / (float)N - mean * mean;
    const float sc   = gamma[d] * rsqrtf(var + 1e-3f);
    const float sh   = beta[d] - mean * sc;

    int i = blockIdx.x * blockDim.x + threadIdx.x;
    int base = i * 4;
    if (base + 3 < N) {
        float4* p = (float4*)(y + (long)d * N + base);
        float4 v = *p;
        v.x = fmaf(v.x, sc, sh);
        v.y = fmaf(v.y, sc, sh);
        v.z = fmaf(v.z, sc, sh);
        v.w = fmaf(v.w, sc, sh);
        *p = v;
    } else if (base < N) {
        for (int t = base; t < N; ++t) y[(long)d * N + t] = fmaf(y[(long)d * N + t], sc, sh);
    }
}

// ---- launcher ----
extern "C" void kernel_launch(void* const* d_in, const int* in_sizes, int n_in,
                              void* d_out, int out_size, void* d_ws, size_t ws_size,
                              hipStream_t stream) {
    const float* data_in = (const float*)d_in[0];
    const int*   neigh   = (const int*)d_in[1];
    const float* weight  = (const float*)d_in[2];
    const float* gamma   = (const float*)d_in[3];
    const float* beta    = (const float*)d_in[4];
    float* out = (float*)d_out;

    const int N = in_sizes[1] / KK;
    const int nblk32 = (N + 31) / 32;        // x-prep tiles
    const int nblk64 = (N + 63) / 64;        // conv blocks (2 waves x 32 nodes)

    char* ws = (char*)d_ws;
    unsigned short* xTb = (unsigned short*)ws;                     // N*32 bf16
    unsigned short* wTb = (unsigned short*)(ws + (size_t)N * 64);  // 27*1024 bf16
    float* tot = (float*)(ws + (size_t)N * 64 + 55296);            // 64 floats

    prep_k<<<KK + nblk32, 256, 0, stream>>>(data_in, weight, xTb, wTb, tot, N);
    conv_k<<<nblk64, 128, 0, stream>>>(xTb, neigh, wTb, out, tot, N);
    dim3 ngrid(((N + 3) / 4 + 255) / 256, 32);
    norm_k<<<ngrid, 256, 0, stream>>>(out, tot, gamma, beta, N);
}